// Round 2
// baseline (114.841 us; speedup 1.0000x reference)
//
#include <hip/hip_runtime.h>

// GHM loss: focal (ch 0) + GHMR (ch 1..7), 3 scalar outputs.
// Pass 1 (streaming, grid-stride):
//   - bin test done algebraically on d^2 vs precomputed thresholds:
//       g*10 >= b  <=>  d^2*(100-b^2) >= b^2*mu^2  <=>  d^2 >= C_b
//     (1 v_cmp per bin, no sqrt/rcp needed for binning)
//   - cumulative counts accumulated on the SCALAR pipe via
//     ballot -> s_bcnt1 -> s_add (wave-uniform SGPR accumulators)
//   - cumulative loss sums: cndmask+add per bin (vector)
//   - valid folded once per channel: d2m = valid ? d^2 : -1, C_0 = -0.5
// Per-block partials in d_ws (deterministic, no atomics).
// Pass 2: 1 block reduces partials and computes the 3 outputs.
//
// Partials layout [quantity][block], NQ = 22:
//   q 0..9  : cumulative loss sums  l_b  (sum of loss where g*10 >= b, valid)
//   q 10    : focal sum
//   q 11    : valid pixel count
//   q 12..21: cumulative counts     c_b  (# valid elems with g*10 >= b)

#define NQ 22

__global__ __launch_bounds__(256)
void ghm_pass1(const float4* __restrict__ preds, const float4* __restrict__ tgts,
               int n_pix, float* __restrict__ part, int nb) {
    constexpr float MU2 = 4.0e-4f;
    // C_b = b^2*MU2/(100-b^2), b=1..9 ; C_0 = -0.5 (valid marker passes)
    const float C[10] = { -0.5f,
                          4.0404041e-6f, 1.6666667e-5f, 3.9560441e-5f,
                          7.6190476e-5f, 1.3333333e-4f, 2.2500000e-4f,
                          3.8431373e-4f, 7.1111111e-4f, 1.7052632e-3f };

    float lac[10];
#pragma unroll
    for (int b = 0; b < 10; ++b) lac[b] = 0.f;
    float facc = 0.f;
    unsigned int cnt[10] = {0,0,0,0,0,0,0,0,0,0};
    unsigned int vcnt = 0;

    const int tid = threadIdx.x;
    const int stride = gridDim.x * 256;
    for (int i = blockIdx.x * 256 + tid; i < n_pix; i += stride) {
        const size_t base = 2 * (size_t)i;
        float4 p0 = preds[base];
        float4 p1 = preds[base + 1];
        float4 t0 = tgts[base];
        float4 t1 = tgts[base + 1];

        // focal (channel 0); y is exactly 0.0 or 1.0
        float x = p0.x, y = t0.x;
        bool valid = y > 0.1f;
        float x_t = valid ? x : 1.f - x;
        float a_t = valid ? 0.25f : 0.75f;
        float om = 1.f - x_t;
        facc += -a_t * om * om * __logf(x_t + 1e-5f);
        vcnt += (unsigned)__popcll(__builtin_amdgcn_ballot_w64(valid));

        float pd[7] = {p0.y, p0.z, p0.w, p1.x, p1.y, p1.z, p1.w};
        float td[7] = {t0.y, t0.z, t0.w, t1.x, t1.y, t1.z, t1.w};
#pragma unroll
        for (int c = 0; c < 7; ++c) {
            float d  = pd[c] - td[c];
            float d2 = d * d;
            float s  = __builtin_sqrtf(__builtin_fmaf(d, d, MU2));
            float loss = s - 0.02f;
            float d2m = valid ? d2 : -1.f;
#pragma unroll
            for (int b = 0; b < 10; ++b) {
                bool pb = d2m >= C[b];
                lac[b] += pb ? loss : 0.f;
                cnt[b] += (unsigned)__popcll(__builtin_amdgcn_ballot_w64(pb));
            }
        }
    }

    // wave (64-lane) shuffle reduction of the 11 vector accumulators
    float vq[11] = { lac[0], lac[1], lac[2], lac[3], lac[4],
                     lac[5], lac[6], lac[7], lac[8], lac[9], facc };
#pragma unroll
    for (int q = 0; q < 11; ++q) {
        float v = vq[q];
        v += __shfl_down(v, 32);
        v += __shfl_down(v, 16);
        v += __shfl_down(v, 8);
        v += __shfl_down(v, 4);
        v += __shfl_down(v, 2);
        v += __shfl_down(v, 1);
        vq[q] = v;
    }

    __shared__ float sm[4][NQ];
    const int wave = tid >> 6, lane = tid & 63;
    if (lane == 0) {
#pragma unroll
        for (int q = 0; q < 11; ++q) sm[wave][q] = vq[q];
        sm[wave][11] = (float)vcnt;
#pragma unroll
        for (int b = 0; b < 10; ++b) sm[wave][12 + b] = (float)cnt[b];
    }
    __syncthreads();
    if (tid < NQ) {
        float v = sm[0][tid] + sm[1][tid] + sm[2][tid] + sm[3][tid];
        part[(size_t)tid * nb + blockIdx.x] = v;
    }
}

__global__ __launch_bounds__(256)
void ghm_final(const float* __restrict__ part, int nb,
               float* __restrict__ out, float inv_npix) {
    __shared__ float red[NQ];
    const int tid = threadIdx.x;
    const int wave = tid >> 6, lane = tid & 63;

    // each wave owns quantities q = wave, wave+4, ... (no sync in loop)
    for (int q = wave; q < NQ; q += 4) {
        float v = 0.f;
        for (int i = lane; i < nb; i += 64) v += part[(size_t)q * nb + i];
        v += __shfl_down(v, 32);
        v += __shfl_down(v, 16);
        v += __shfl_down(v, 8);
        v += __shfl_down(v, 4);
        v += __shfl_down(v, 2);
        v += __shfl_down(v, 1);
        if (lane == 0) red[q] = v;
    }
    __syncthreads();

    if (tid == 0) {
        float tot = fmaxf(red[11], 1.f);
        float n = 0.f, sum = 0.f;
#pragma unroll
        for (int b = 0; b < 10; ++b) {
            float cb = red[12 + b] - (b < 9 ? red[12 + b + 1] : 0.f);
            float lb = red[b]      - (b < 9 ? red[b + 1]      : 0.f);
            if (cb > 0.f) {
                n += 1.f;
                sum += tot / fmaxf(0.3f * cb, 1e-30f) * lb;
            }
        }
        float reg = sum / fmaxf(n, 1.f) / tot;
        float cls = red[10] * inv_npix;
        out[0] = cls + reg;
        out[1] = reg;
        out[2] = cls;
    }
}

extern "C" void kernel_launch(void* const* d_in, const int* in_sizes, int n_in,
                              void* d_out, int out_size, void* d_ws, size_t ws_size,
                              hipStream_t stream) {
    const float* preds = (const float*)d_in[0];
    const float* tgts  = (const float*)d_in[1];
    const int n_pix = in_sizes[0] / 8;

    size_t nb_max = ws_size / (NQ * sizeof(float));
    int nb = (int)(nb_max < 2048 ? nb_max : 2048);
    if (nb < 1) nb = 1;

    float* part = (float*)d_ws;
    ghm_pass1<<<nb, 256, 0, stream>>>((const float4*)preds, (const float4*)tgts,
                                      n_pix, part, nb);
    ghm_final<<<1, 256, 0, stream>>>(part, nb, (float*)d_out,
                                     1.f / (float)n_pix);
}